// Round 1
// baseline (1622.391 us; speedup 1.0000x reference)
//
#include <hip/hip_runtime.h>
#include <hip/hip_bf16.h>
#include <math.h>

// Problem constants (match reference)
#define N_PIX   262144
#define G_NUM   4096
#define K_FREQ  4
#define GSTRIDE 32      // floats per packed gaussian record (128 B)
#define TG      128     // gaussians per LDS tile (16 KB)
#define BLOCK   256
#define PPT     2       // pixels per thread

#if __has_builtin(__builtin_amdgcn_exp2f)
#define EXP2F(x) __builtin_amdgcn_exp2f(x)
#else
#define EXP2F(x) exp2f(x)
#endif

// cos(2*pi*v): v_cos_f32 takes revolutions; v_fract_f32 does range reduction.
__device__ __forceinline__ float cos2pi(float v) {
    return __builtin_amdgcn_cosf(__builtin_amdgcn_fractf(v));
}

// Pack per-gaussian params into a 32-float record:
// [0..3]  px, py, cos(rot), sin(rot)
// [4..7]  isx*S, isy*S, color0, color1      (S = sqrt(0.5*log2(e)))
// [8..11] color2, 0, 0, 0
// [12..15] fx[0..3]   (frequency in revolutions-per-unit-tx, = idx * MAXF/NF)
// [16..19] cx[0..3]
// [20..23] fy[0..3]
// [24..27] cy[0..3]
// [28..31] pad
__global__ void prep_kernel(const float* __restrict__ colors,
                            const float* __restrict__ pos,
                            const float* __restrict__ scales,
                            const float* __restrict__ rots,
                            const float* __restrict__ coeffs,
                            const int*   __restrict__ idx,
                            float* __restrict__ gp)
{
    int g = blockIdx.x * blockDim.x + threadIdx.x;
    if (g >= G_NUM) return;
    float sr, cr;
    sincosf(rots[g], &sr, &cr);
    // fold exp(-0.5*u) = exp2(-(sqrt(0.5*log2e)*sqrt(u))^2) into the scales
    const float SC = 0.84932180028801904f;   // sqrt(0.5 * log2(e))
    float isx = expf(scales[2*g + 0]) * SC;
    float isy = expf(scales[2*g + 1]) * SC;
    float* o = gp + (size_t)g * GSTRIDE;
    o[0] = pos[2*g];  o[1] = pos[2*g + 1];  o[2] = cr;  o[3] = sr;
    o[4] = isx;       o[5] = isy;
    o[6] = colors[3*g];  o[7] = colors[3*g + 1];
    o[8] = colors[3*g + 2];  o[9] = 0.f;  o[10] = 0.f;  o[11] = 0.f;
    const float FS = 1024.0f / 1024.0f;   // MAXF / NF
#pragma unroll
    for (int k = 0; k < K_FREQ; ++k) {
        o[12 + k] = (float)idx[g*2*K_FREQ + 2*k + 0] * FS;
        o[16 + k] = coeffs[g*2*K_FREQ + 2*k + 0];
        o[20 + k] = (float)idx[g*2*K_FREQ + 2*k + 1] * FS;
        o[24 + k] = coeffs[g*2*K_FREQ + 2*k + 1];
    }
    o[28] = 0.f; o[29] = 0.f; o[30] = 0.f; o[31] = 0.f;
}

__global__ __launch_bounds__(BLOCK) void render_kernel(
    const float* __restrict__ x,
    const float* __restrict__ gp,
    float* __restrict__ out)
{
    __shared__ __align__(16) float sg[TG * GSTRIDE];
    const int tid  = threadIdx.x;
    const int pix0 = blockIdx.x * (BLOCK * PPT) + tid;   // second pixel: pix0 + BLOCK

    const float2* __restrict__ x2 = (const float2*)x;
    const float2 P0 = x2[pix0];
    const float2 P1 = x2[pix0 + BLOCK];

    float a0 = 0.f, a1 = 0.f, a2 = 0.f;   // pixel 0 RGB
    float b0 = 0.f, b1 = 0.f, b2 = 0.f;   // pixel 1 RGB

    for (int base = 0; base < G_NUM; base += TG) {
        __syncthreads();
        {   // cooperative stage: TG*32 floats = 1024 float4, 4 per thread
            const float4* __restrict__ src = (const float4*)(gp + (size_t)base * GSTRIDE);
            float4* dst = (float4*)sg;
#pragma unroll
            for (int j = 0; j < (TG * GSTRIDE / 4) / BLOCK; ++j)
                dst[tid + j * BLOCK] = src[tid + j * BLOCK];
        }
        __syncthreads();

#pragma unroll 2
        for (int t = 0; t < TG; ++t) {
            const float* q = sg + t * GSTRIDE;
            const float4 A  = *(const float4*)(q + 0);    // px, py, cr, sr
            const float4 Bv = *(const float4*)(q + 4);    // isx, isy, c0, c1
            const float  c2 = q[8];
            const float4 FX = *(const float4*)(q + 12);
            const float4 CX = *(const float4*)(q + 16);
            const float4 FY = *(const float4*)(q + 20);
            const float4 CY = *(const float4*)(q + 24);

            // ---- pixel 0 ----
            {
                float dx = P0.x - A.x, dy = P0.y - A.y;
                float tx = dx * A.z + dy * A.w;
                float ty = dy * A.z - dx * A.w;
                float bx = tx * Bv.x, by = ty * Bv.y;
                float gw = EXP2F(-(bx * bx + by * by));
                float wx;
                wx  = CX.x * cos2pi(tx * FX.x);
                wx += CX.y * cos2pi(tx * FX.y);
                wx += CX.z * cos2pi(tx * FX.z);
                wx += CX.w * cos2pi(tx * FX.w);
                float wy;
                wy  = CY.x * cos2pi(ty * FY.x);
                wy += CY.y * cos2pi(ty * FY.y);
                wy += CY.z * cos2pi(ty * FY.z);
                wy += CY.w * cos2pi(ty * FY.w);
                float w = gw * wx * wy;
                a0 += w * Bv.z; a1 += w * Bv.w; a2 += w * c2;
            }
            // ---- pixel 1 ----
            {
                float dx = P1.x - A.x, dy = P1.y - A.y;
                float tx = dx * A.z + dy * A.w;
                float ty = dy * A.z - dx * A.w;
                float bx = tx * Bv.x, by = ty * Bv.y;
                float gw = EXP2F(-(bx * bx + by * by));
                float wx;
                wx  = CX.x * cos2pi(tx * FX.x);
                wx += CX.y * cos2pi(tx * FX.y);
                wx += CX.z * cos2pi(tx * FX.z);
                wx += CX.w * cos2pi(tx * FX.w);
                float wy;
                wy  = CY.x * cos2pi(ty * FY.x);
                wy += CY.y * cos2pi(ty * FY.y);
                wy += CY.z * cos2pi(ty * FY.z);
                wy += CY.w * cos2pi(ty * FY.w);
                float w = gw * wx * wy;
                b0 += w * Bv.z; b1 += w * Bv.w; b2 += w * c2;
            }
        }
    }

    const int o0 = pix0 * 3;
    out[o0 + 0] = a0; out[o0 + 1] = a1; out[o0 + 2] = a2;
    const int o1 = (pix0 + BLOCK) * 3;
    out[o1 + 0] = b0; out[o1 + 1] = b1; out[o1 + 2] = b2;
}

extern "C" void kernel_launch(void* const* d_in, const int* in_sizes, int n_in,
                              void* d_out, int out_size, void* d_ws, size_t ws_size,
                              hipStream_t stream) {
    const float* x      = (const float*)d_in[0];   // [N,2]
    const float* colors = (const float*)d_in[1];   // [G,3]
    const float* pos    = (const float*)d_in[2];   // [G,2]
    const float* scales = (const float*)d_in[3];   // [G,2]
    const float* rots   = (const float*)d_in[4];   // [G,1]
    const float* coeffs = (const float*)d_in[5];   // [G,K,2]
    const int*   idx    = (const int*)d_in[6];     // [G,K,2]
    float* out = (float*)d_out;
    float* gp  = (float*)d_ws;                     // needs G*32*4 = 512 KB

    prep_kernel<<<(G_NUM + 255) / 256, 256, 0, stream>>>(
        colors, pos, scales, rots, coeffs, idx, gp);
    render_kernel<<<N_PIX / (BLOCK * PPT), BLOCK, 0, stream>>>(x, gp, out);
}